// Round 9
// baseline (510.151 us; speedup 1.0000x reference)
//
#include <hip/hip_runtime.h>
#include <hip/hip_bf16.h>

#define Hdim 256
#define Bdim 16
#define Lleaf 4096

typedef unsigned short u16;
typedef __attribute__((ext_vector_type(8))) short short8;
typedef __attribute__((ext_vector_type(4))) float f32x4;

__device__ __forceinline__ u16 f2bf(float x) {
    __hip_bfloat16 b = __float2bfloat16(x);
    return *(u16*)&b;
}
__device__ __forceinline__ float bf2f(u16 u) {
    __hip_bfloat16 b = *(__hip_bfloat16*)&u;
    return __bfloat162float(b);
}
__device__ __forceinline__ float fsig(float x) { return 1.0f / (1.0f + __expf(-x)); }
__device__ __forceinline__ float ftanh(float x) {
    float e = __expf(-2.0f * fabsf(x));
    float t = (1.0f - e) / (1.0f + e);
    return copysignf(t, x);
}

__device__ __forceinline__ void gload_lds16(const u16* gsrc, u16* ldsdst) {
    __builtin_amdgcn_global_load_lds(
        (const __attribute__((address_space(1))) unsigned int*)gsrc,
        (__attribute__((address_space(3))) unsigned int*)ldsdst, 16, 0, 0);
}

// ---------------- weight pack, fragment-major: Wpk[ng][c32][g][t][512] ----------------
// elem (lane,j): n = ng*16 + (lane&15), k = c32*32 + (lane>>4)*8 + j
__global__ void pack_weights2(const float* __restrict__ Wfl, const float* __restrict__ Wfr,
                              const float* __restrict__ Wi,  const float* __restrict__ Wo,
                              const float* __restrict__ Wc,
                              u16* __restrict__ Wpk)
{
    int blk = blockIdx.x;            // 0..255 = ng*16 + c32
    int ng = blk >> 4, c = blk & 15;
    for (int e = threadIdx.x; e < 5120; e += 256) {
        int g = e >> 10, r = e & 1023;
        int t = r >> 9, s = r & 511;
        int lane = s >> 3, j = s & 7;
        int n = ng * 16 + (lane & 15);
        int k = c * 32 + (lane >> 4) * 8 + j;
        const float* W = (g == 0) ? Wfl : (g == 1) ? Wfr : (g == 2) ? Wi : (g == 3) ? Wo : Wc;
        float x = W[(size_t)k * Hdim + n];
        u16 hi = f2bf(x);
        u16 v = t ? f2bf(x - bf2f(hi)) : hi;
        Wpk[(size_t)blk * 5120 + e] = v;
    }
}

// ---------------- W_proj pack, fragment-major: Wppk[ng][c32][t][512], c32=0..7 ----------------
__global__ void pack_wp2(const float* __restrict__ Wp, u16* __restrict__ Wppk)
{
    int blk = blockIdx.x;            // 0..127 = ng*8 + c32
    int ng = blk >> 3, c = blk & 7;
    for (int e = threadIdx.x; e < 1024; e += 256) {
        int t = e >> 9, s = e & 511;
        int lane = s >> 3, j = s & 7;
        int n = ng * 16 + (lane & 15);
        int k = c * 32 + (lane >> 4) * 8 + j;
        float x = Wp[(size_t)k * Hdim + n];
        u16 hi = f2bf(x);
        u16 v = t ? f2bf(x - bf2f(hi)) : hi;
        Wppk[(size_t)blk * 1024 + e] = v;
    }
}

// ---------------- leaf via MFMA: no LDS, no barriers, B direct from packed Wp ----------------
__global__ __launch_bounds__(256, 2) void leaf_mfma2(
    const int* __restrict__ ids, const float* __restrict__ emb,
    const u16* __restrict__ Wppk, const float* __restrict__ bp,
    u16* __restrict__ A0hi)
{
    int tid = threadIdx.x;
    int lane = tid & 63, w = tid >> 6;
    int l16 = lane & 15, quad = lane >> 4;
    int m0 = blockIdx.x * 128, ny = blockIdx.y;
    int n0 = ny * 64;

    const float* aptr[2];
#pragma unroll
    for (int mt = 0; mt < 2; mt++) {
        int m = m0 + w * 32 + mt * 16 + l16;
        aptr[mt] = emb + (size_t)ids[m] * 256 + quad * 8;
    }

    f32x4 acc[2][4];
    f32x4 zf = {0.f, 0.f, 0.f, 0.f};
#pragma unroll
    for (int i = 0; i < 2; i++)
#pragma unroll
        for (int j = 0; j < 4; j++) acc[i][j] = zf;

#pragma unroll 1
    for (int c = 0; c < 8; c++) {
        int k0 = c * 32;
        short8 bh[4], bl[4];
#pragma unroll
        for (int nt = 0; nt < 4; nt++) {
            const u16* pb = Wppk + (size_t)(((ny * 4 + nt) * 8 + c) * 2) * 512 + lane * 8;
            bh[nt] = *(const short8*)(pb);
            bl[nt] = *(const short8*)(pb + 512);
        }
        short8 ah[2], al[2];
#pragma unroll
        for (int mt = 0; mt < 2; mt++) {
            float4 a0 = *(const float4*)(aptr[mt] + k0);
            float4 a1 = *(const float4*)(aptr[mt] + k0 + 4);
            float fv[8] = {a0.x, a0.y, a0.z, a0.w, a1.x, a1.y, a1.z, a1.w};
#pragma unroll
            for (int e = 0; e < 8; e++) {
                u16 hv = f2bf(fv[e]);
                u16 lv = f2bf(fv[e] - bf2f(hv));
                ah[mt][e] = (short)hv;
                al[mt][e] = (short)lv;
            }
        }
#pragma unroll
        for (int nt = 0; nt < 4; nt++)
#pragma unroll
            for (int mt = 0; mt < 2; mt++) {
                acc[mt][nt] = __builtin_amdgcn_mfma_f32_16x16x32_bf16(ah[mt], bh[nt], acc[mt][nt], 0, 0, 0);
                acc[mt][nt] = __builtin_amdgcn_mfma_f32_16x16x32_bf16(al[mt], bh[nt], acc[mt][nt], 0, 0, 0);
                acc[mt][nt] = __builtin_amdgcn_mfma_f32_16x16x32_bf16(ah[mt], bl[nt], acc[mt][nt], 0, 0, 0);
            }
    }
#pragma unroll
    for (int mt = 0; mt < 2; mt++)
#pragma unroll
        for (int nt = 0; nt < 4; nt++)
#pragma unroll
            for (int r = 0; r < 4; r++) {
                int m = m0 + w * 32 + mt * 16 + quad * 4 + r;
                int n = n0 + nt * 16 + l16;
                float h = acc[mt][nt][r] + bp[n];
                A0hi[(size_t)(m >> 1) * 512 + (m & 1) * 256 + n] = f2bf(h);
            }
}

// ---------------- big level (M >= 4096): 2-term, BK=64, wave tile 64m x 32n ----------------
// Block 128m x 64n x 5g; 4 waves = 2 m-halves x 2 n-halves. Each wave reads only its
// m-half's A frags from LDS (8/chunk, was 16) and each A frag feeds 20 MFMAs (was 10).
// A staged dbuf LDS via global_load_lds; B direct global->VGPR from packed weights.
template <int LEAF>
__global__ __launch_bounds__(256, 2) void level_big(
    const u16* __restrict__ Ahi,
    const float* __restrict__ Cin,
    const u16* __restrict__ Wpk,
    const float* __restrict__ bfl, const float* __restrict__ bfr,
    const float* __restrict__ bi,  const float* __restrict__ bo,
    const float* __restrict__ bc,
    u16* __restrict__ Aohi, u16* __restrict__ Aolo, float* __restrict__ Cout,
    int M)
{
    int tid = threadIdx.x;
    int lane = tid & 63, w = tid >> 6;
    int l16 = lane & 15, quad = lane >> 4;
    int m0 = blockIdx.x * 128, n0 = blockIdx.y * 64;
    int mh = w >> 1, nh = w & 1;
    int ngb = blockIdx.y * 4 + nh * 2;     // first of this wave's two n-16 groups

    __shared__ u16 Abuf[2][16 * 512];      // 2 x 16 KB (k64 chunk = 16 frags)

    // staging: frag fj = w*4+i -> sub s = fj>>3, mf = fj&7 (frag stored at index s*8+mf)
    const u16* asrc[4];
#pragma unroll
    for (int i = 0; i < 4; i++) {
        int fj = w * 4 + i;
        int s = fj >> 3, mf = fj & 7;
        int row = min(m0 + mf * 16 + l16, M - 1);
        asrc[i] = Ahi + (size_t)row * 512 + quad * 8 + s * 32;
    }
    const u16* pb[2];
    pb[0] = Wpk + (size_t)ngb * 16 * 5120 + lane * 8;
    pb[1] = pb[0] + 16 * 5120;

    f32x4 acc[5][4][2];                    // [g][mfi][nt]
    f32x4 zf = {0.f, 0.f, 0.f, 0.f};
#pragma unroll
    for (int g = 0; g < 5; g++)
#pragma unroll
        for (int i = 0; i < 4; i++)
#pragma unroll
            for (int j = 0; j < 2; j++) acc[g][i][j] = zf;

    // prologue: stage chunk 0
#pragma unroll
    for (int i = 0; i < 4; i++)
        gload_lds16(asrc[i], &Abuf[0][(w * 4 + i) * 512]);

#pragma unroll 1
    for (int c = 0; c < 8; c++) {
        __syncthreads();
        if (c < 7) {
#pragma unroll
            for (int i = 0; i < 4; i++)
                gload_lds16(asrc[i] + (c + 1) * 64, &Abuf[(c + 1) & 1][(w * 4 + i) * 512]);
        }
        const u16* ab = &Abuf[c & 1][0];
#pragma unroll
        for (int s = 0; s < 2; s++) {
            int c32 = c * 2 + s;
            short8 ah[4];
#pragma unroll
            for (int mfi = 0; mfi < 4; mfi++)
                ah[mfi] = *(const short8*)&ab[(s * 8 + mh * 4 + mfi) * 512 + lane * 8];
#pragma unroll
            for (int nt = 0; nt < 2; nt++) {
                short8 bh[5], bl[5];
#pragma unroll
                for (int g = 0; g < 5; g++) {
                    bh[g] = *(const short8*)(pb[nt] + (size_t)(c32 * 10 + g * 2) * 512);
                    bl[g] = *(const short8*)(pb[nt] + (size_t)(c32 * 10 + g * 2 + 1) * 512);
                }
#pragma unroll
                for (int mfi = 0; mfi < 4; mfi++)
#pragma unroll
                    for (int g = 0; g < 5; g++) {
                        acc[g][mfi][nt] = __builtin_amdgcn_mfma_f32_16x16x32_bf16(ah[mfi], bh[g], acc[g][mfi][nt], 0, 0, 0);
                        acc[g][mfi][nt] = __builtin_amdgcn_mfma_f32_16x16x32_bf16(ah[mfi], bl[g], acc[g][mfi][nt], 0, 0, 0);
                    }
            }
        }
    }

    // epilogue: wave-local combine (wave owns 64m x 32n, all gates)
#pragma unroll
    for (int nt = 0; nt < 2; nt++) {
        int n = n0 + nh * 32 + nt * 16 + l16;
#pragma unroll
        for (int mfi = 0; mfi < 4; mfi++)
#pragma unroll
            for (int r = 0; r < 4; r++) {
                int m = m0 + mh * 64 + mfi * 16 + quad * 4 + r;
                if (m >= M) continue;
                float fl = fsig(acc[0][mfi][nt][r] + bfl[n]);
                float fr = fsig(acc[1][mfi][nt][r] + bfr[n]);
                float ig = fsig(acc[2][mfi][nt][r] + bi[n]);
                float og = fsig(acc[3][mfi][nt][r] + bo[n]);
                float cc = ftanh(acc[4][mfi][nt][r] + bc[n]);
                float cl, cr;
                if (LEAF) {
                    cl = ftanh(bf2f(Ahi[(size_t)m * 512 + n]));
                    cr = ftanh(bf2f(Ahi[(size_t)m * 512 + 256 + n]));
                } else {
                    cl = Cin[(size_t)(2 * m) * 256 + n];
                    cr = Cin[(size_t)(2 * m + 1) * 256 + n];
                }
                float cn = fl * cl + fr * cr + ig * cc;
                Cout[(size_t)m * 256 + n] = cn;
                float h = og * ftanh(cn);
                u16 hh = f2bf(h);
                u16 hl = f2bf(h - bf2f(hh));
                size_t ai = (size_t)(m >> 1) * 512 + (m & 1) * 256 + n;
                Aohi[ai] = hh;
                Aolo[ai] = hl;
            }
    }
}

// ---------------- small level (M <= 2048): block = 16m x 16n x 5g, waves split K, 3-term -------
__global__ __launch_bounds__(256, 4) void level_small(
    const u16* __restrict__ Ahi, const u16* __restrict__ Alo,
    const float* __restrict__ Cin,
    const u16* __restrict__ Wpk,
    const float* __restrict__ bfl, const float* __restrict__ bfr,
    const float* __restrict__ bi,  const float* __restrict__ bo,
    const float* __restrict__ bc,
    u16* __restrict__ Aohi, u16* __restrict__ Aolo, float* __restrict__ Cout,
    int M)
{
    int tid = threadIdx.x;
    int lane = tid & 63, w = tid >> 6;
    int l16 = lane & 15, quad = lane >> 4;
    int mb = blockIdx.x * 16;
    int ng = blockIdx.y;

    const u16* pah = Ahi + (size_t)(mb + l16) * 512 + quad * 8;
    const u16* pal = Alo + (size_t)(mb + l16) * 512 + quad * 8;
    const u16* pb  = Wpk + (size_t)ng * 16 * 5120 + lane * 8;

    f32x4 acc[5];
    f32x4 zf = {0.f, 0.f, 0.f, 0.f};
#pragma unroll
    for (int g = 0; g < 5; g++) acc[g] = zf;

#pragma unroll
    for (int i = 0; i < 4; i++) {
        int c = w * 4 + i;
        short8 ah = *(const short8*)(pah + c * 32);
        short8 al = *(const short8*)(pal + c * 32);
#pragma unroll
        for (int g = 0; g < 5; g++) {
            short8 bh = *(const short8*)(pb + (size_t)(c * 10 + g * 2) * 512);
            short8 bl = *(const short8*)(pb + (size_t)(c * 10 + g * 2 + 1) * 512);
            acc[g] = __builtin_amdgcn_mfma_f32_16x16x32_bf16(ah, bh, acc[g], 0, 0, 0);
            acc[g] = __builtin_amdgcn_mfma_f32_16x16x32_bf16(al, bh, acc[g], 0, 0, 0);
            acc[g] = __builtin_amdgcn_mfma_f32_16x16x32_bf16(ah, bl, acc[g], 0, 0, 0);
        }
    }

    __shared__ float red[4][5][256];   // 20 KB
#pragma unroll
    for (int g = 0; g < 5; g++)
#pragma unroll
        for (int r = 0; r < 4; r++)
            red[w][g][(quad * 4 + r) * 16 + l16] = acc[g][r];
    __syncthreads();

    int m = mb + (tid >> 4);
    int n = ng * 16 + (tid & 15);
    if (m < M) {
        float z[5];
#pragma unroll
        for (int g = 0; g < 5; g++)
            z[g] = red[0][g][tid] + red[1][g][tid] + red[2][g][tid] + red[3][g][tid];
        float fl = fsig(z[0] + bfl[n]);
        float fr = fsig(z[1] + bfr[n]);
        float ig = fsig(z[2] + bi[n]);
        float og = fsig(z[3] + bo[n]);
        float cc = ftanh(z[4] + bc[n]);
        float cl = Cin[(size_t)(2 * m) * 256 + n];
        float cr = Cin[(size_t)(2 * m + 1) * 256 + n];
        float cn = fl * cl + fr * cr + ig * cc;
        Cout[(size_t)m * 256 + n] = cn;
        float h = og * ftanh(cn);
        u16 hh = f2bf(h);
        u16 hl = f2bf(h - bf2f(hh));
        size_t ai = (size_t)(m >> 1) * 512 + (m & 1) * 256 + n;
        Aohi[ai] = hh;
        Aolo[ai] = hl;
    }
}

// ---------------- classifier ----------------
__global__ void classifier_bf(const u16* __restrict__ Ahi, const u16* __restrict__ Alo,
                              const float* __restrict__ Wcls, const float* __restrict__ bcls,
                              float* __restrict__ out)
{
    int t = threadIdx.x;
    if (t < Bdim * 2) {
        int b = t >> 1, cls = t & 1;
        float s = bcls[cls];
        for (int n = 0; n < Hdim; n++) {
            size_t ai = (size_t)(b >> 1) * 512 + (b & 1) * 256 + n;
            float h = bf2f(Ahi[ai]) + bf2f(Alo[ai]);
            s += h * Wcls[(size_t)n * 2 + cls];
        }
        out[t] = s;
    }
}

extern "C" void kernel_launch(void* const* d_in, const int* in_sizes, int n_in,
                              void* d_out, int out_size, void* d_ws, size_t ws_size,
                              hipStream_t stream) {
    const int*   ids  = (const int*)d_in[0];
    const float* emb  = (const float*)d_in[1];
    const float* Wp   = (const float*)d_in[2];
    const float* bp   = (const float*)d_in[3];
    const float* Wfl  = (const float*)d_in[4];
    const float* bfl  = (const float*)d_in[5];
    const float* Wfr  = (const float*)d_in[6];
    const float* bfr  = (const float*)d_in[7];
    const float* Wi   = (const float*)d_in[8];
    const float* bi   = (const float*)d_in[9];
    const float* Wo   = (const float*)d_in[10];
    const float* bo   = (const float*)d_in[11];
    const float* Wc   = (const float*)d_in[12];
    const float* bc   = (const float*)d_in[13];
    const float* Wcls = (const float*)d_in[14];
    const float* bcls = (const float*)d_in[15];

    u16* Wpk  = (u16*)d_ws;
    u16* Wppk = Wpk + (size_t)256 * 5120;
    unsigned char* base = (unsigned char*)d_ws + (4u << 20);
    unsigned char* R1 = base;
    unsigned char* R2 = base + 33554432;

    pack_weights2<<<256, 256, 0, stream>>>(Wfl, Wfr, Wi, Wo, Wc, Wpk);
    pack_wp2<<<128, 256, 0, stream>>>(Wp, Wppk);

    int M0 = Bdim * Lleaf;
    leaf_mfma2<<<dim3(M0 / 128, 4), 256, 0, stream>>>(ids, emb, Wppk, bp, (u16*)R1);

    const u16* Ain_hi = (const u16*)R1;
    const u16* Ain_lo = nullptr;
    const float* Cin = nullptr;

    int lev = 1;
    for (int M = 32768; M >= 16; M >>= 1, lev++) {
        unsigned char* ob = (lev & 1) ? R2 : R1;
        u16* Aohi = (u16*)ob;
        u16* Aolo = Aohi + (size_t)M * 256;
        float* Cout = (float*)(Aohi + (size_t)M * 512);
        if (lev == 1) {
            level_big<1><<<dim3(M / 128, 4), 256, 0, stream>>>(Ain_hi, nullptr, Wpk,
                                                               bfl, bfr, bi, bo, bc, Aohi, Aolo, Cout, M);
        } else if (M >= 4096) {
            level_big<0><<<dim3(M / 128, 4), 256, 0, stream>>>(Ain_hi, Cin, Wpk,
                                                               bfl, bfr, bi, bo, bc, Aohi, Aolo, Cout, M);
        } else {
            level_small<<<dim3(M / 16, 16), 256, 0, stream>>>(Ain_hi, Ain_lo, Cin, Wpk,
                                                              bfl, bfr, bi, bo, bc, Aohi, Aolo, Cout, M);
        }
        Ain_hi = Aohi; Ain_lo = Aolo; Cin = Cout;
    }

    classifier_bf<<<1, 64, 0, stream>>>(Ain_hi, Ain_lo, Wcls, bcls, (float*)d_out);
}

// Round 10
// 439.675 us; speedup vs baseline: 1.1603x; 1.1603x over previous
//
#include <hip/hip_runtime.h>
#include <hip/hip_bf16.h>

#define Hdim 256
#define Bdim 16
#define Lleaf 4096

typedef unsigned short u16;
typedef __attribute__((ext_vector_type(8))) short short8;
typedef __attribute__((ext_vector_type(4))) float f32x4;

__device__ __forceinline__ u16 f2bf(float x) {
    __hip_bfloat16 b = __float2bfloat16(x);
    return *(u16*)&b;
}
__device__ __forceinline__ float bf2f(u16 u) {
    __hip_bfloat16 b = *(__hip_bfloat16*)&u;
    return __bfloat162float(b);
}
__device__ __forceinline__ float fsig(float x) { return 1.0f / (1.0f + __expf(-x)); }
__device__ __forceinline__ float ftanh(float x) {
    float e = __expf(-2.0f * fabsf(x));
    float t = (1.0f - e) / (1.0f + e);
    return copysignf(t, x);
}

__device__ __forceinline__ void gload_lds16(const u16* gsrc, u16* ldsdst) {
    __builtin_amdgcn_global_load_lds(
        (const __attribute__((address_space(1))) unsigned int*)gsrc,
        (__attribute__((address_space(3))) unsigned int*)ldsdst, 16, 0, 0);
}

// ---------------- weight pack, fragment-major: Wpk[ng][c32][g][t][512] ----------------
// elem (lane,j): n = ng*16 + (lane&15), k = c32*32 + (lane>>4)*8 + j
__global__ void pack_weights2(const float* __restrict__ Wfl, const float* __restrict__ Wfr,
                              const float* __restrict__ Wi,  const float* __restrict__ Wo,
                              const float* __restrict__ Wc,
                              u16* __restrict__ Wpk)
{
    int blk = blockIdx.x;            // 0..255 = ng*16 + c32
    int ng = blk >> 4, c = blk & 15;
    for (int e = threadIdx.x; e < 5120; e += 256) {
        int g = e >> 10, r = e & 1023;
        int t = r >> 9, s = r & 511;
        int lane = s >> 3, j = s & 7;
        int n = ng * 16 + (lane & 15);
        int k = c * 32 + (lane >> 4) * 8 + j;
        const float* W = (g == 0) ? Wfl : (g == 1) ? Wfr : (g == 2) ? Wi : (g == 3) ? Wo : Wc;
        float x = W[(size_t)k * Hdim + n];
        u16 hi = f2bf(x);
        u16 v = t ? f2bf(x - bf2f(hi)) : hi;
        Wpk[(size_t)blk * 5120 + e] = v;
    }
}

// ---------------- W_proj pack, fragment-major: Wppk[ng][c32][t][512], c32=0..7 ----------------
__global__ void pack_wp2(const float* __restrict__ Wp, u16* __restrict__ Wppk)
{
    int blk = blockIdx.x;            // 0..127 = ng*8 + c32
    int ng = blk >> 3, c = blk & 7;
    for (int e = threadIdx.x; e < 1024; e += 256) {
        int t = e >> 9, s = e & 511;
        int lane = s >> 3, j = s & 7;
        int n = ng * 16 + (lane & 15);
        int k = c * 32 + (lane >> 4) * 8 + j;
        float x = Wp[(size_t)k * Hdim + n];
        u16 hi = f2bf(x);
        u16 v = t ? f2bf(x - bf2f(hi)) : hi;
        Wppk[(size_t)blk * 1024 + e] = v;
    }
}

// ---------------- leaf via MFMA: no LDS, no barriers, B direct from packed Wp (3-term) ---------
__global__ __launch_bounds__(256, 2) void leaf_mfma2(
    const int* __restrict__ ids, const float* __restrict__ emb,
    const u16* __restrict__ Wppk, const float* __restrict__ bp,
    u16* __restrict__ A0hi)
{
    int tid = threadIdx.x;
    int lane = tid & 63, w = tid >> 6;
    int l16 = lane & 15, quad = lane >> 4;
    int m0 = blockIdx.x * 128, ny = blockIdx.y;
    int n0 = ny * 64;

    const float* aptr[2];
#pragma unroll
    for (int mt = 0; mt < 2; mt++) {
        int m = m0 + w * 32 + mt * 16 + l16;
        aptr[mt] = emb + (size_t)ids[m] * 256 + quad * 8;
    }

    f32x4 acc[2][4];
    f32x4 zf = {0.f, 0.f, 0.f, 0.f};
#pragma unroll
    for (int i = 0; i < 2; i++)
#pragma unroll
        for (int j = 0; j < 4; j++) acc[i][j] = zf;

#pragma unroll 1
    for (int c = 0; c < 8; c++) {
        int k0 = c * 32;
        short8 bh[4], bl[4];
#pragma unroll
        for (int nt = 0; nt < 4; nt++) {
            const u16* pb = Wppk + (size_t)(((ny * 4 + nt) * 8 + c) * 2) * 512 + lane * 8;
            bh[nt] = *(const short8*)(pb);
            bl[nt] = *(const short8*)(pb + 512);
        }
        short8 ah[2], al[2];
#pragma unroll
        for (int mt = 0; mt < 2; mt++) {
            float4 a0 = *(const float4*)(aptr[mt] + k0);
            float4 a1 = *(const float4*)(aptr[mt] + k0 + 4);
            float fv[8] = {a0.x, a0.y, a0.z, a0.w, a1.x, a1.y, a1.z, a1.w};
#pragma unroll
            for (int e = 0; e < 8; e++) {
                u16 hv = f2bf(fv[e]);
                u16 lv = f2bf(fv[e] - bf2f(hv));
                ah[mt][e] = (short)hv;
                al[mt][e] = (short)lv;
            }
        }
#pragma unroll
        for (int nt = 0; nt < 4; nt++)
#pragma unroll
            for (int mt = 0; mt < 2; mt++) {
                acc[mt][nt] = __builtin_amdgcn_mfma_f32_16x16x32_bf16(ah[mt], bh[nt], acc[mt][nt], 0, 0, 0);
                acc[mt][nt] = __builtin_amdgcn_mfma_f32_16x16x32_bf16(al[mt], bh[nt], acc[mt][nt], 0, 0, 0);
                acc[mt][nt] = __builtin_amdgcn_mfma_f32_16x16x32_bf16(ah[mt], bl[nt], acc[mt][nt], 0, 0, 0);
            }
    }
#pragma unroll
    for (int mt = 0; mt < 2; mt++)
#pragma unroll
        for (int nt = 0; nt < 4; nt++)
#pragma unroll
            for (int r = 0; r < 4; r++) {
                int m = m0 + w * 32 + mt * 16 + quad * 4 + r;
                int n = n0 + nt * 16 + l16;
                float h = acc[mt][nt][r] + bp[n];
                A0hi[(size_t)(m >> 1) * 512 + (m & 1) * 256 + n] = f2bf(h);
            }
}

// ---------------- big level (M >= 4096): 1-term bf16 GEMM (A-hi x W-hi), BK=64 ----------------
// R8 wave decomposition (n-split, wave owns all 128m + its 16n + all gates), rolled loop,
// A dbuf LDS via global_load_lds, B direct global->VGPR (hi stream only).
template <int LEAF>
__global__ __launch_bounds__(256, 2) void level_big(
    const u16* __restrict__ Ahi,
    const float* __restrict__ Cin,
    const u16* __restrict__ Wpk,
    const float* __restrict__ bfl, const float* __restrict__ bfr,
    const float* __restrict__ bi,  const float* __restrict__ bo,
    const float* __restrict__ bc,
    u16* __restrict__ Aohi, u16* __restrict__ Aolo, float* __restrict__ Cout,
    int M)
{
    int tid = threadIdx.x;
    int lane = tid & 63, w = tid >> 6;
    int l16 = lane & 15, quad = lane >> 4;
    int m0 = blockIdx.x * 128, n0 = blockIdx.y * 64;
    int ng = blockIdx.y * 4 + w;

    __shared__ u16 Abuf[2][16 * 512];      // 2 x 16 KB (k64 chunk = 16 frags)

    // per-wave A staging: 4 frags per k64 chunk; frag fj = w*4+i -> sub s = fj>>3, mf = fj&7
    const u16* asrc[4];
#pragma unroll
    for (int i = 0; i < 4; i++) {
        int fj = w * 4 + i;
        int s = fj >> 3, mf = fj & 7;
        int row = min(m0 + mf * 16 + l16, M - 1);
        asrc[i] = Ahi + (size_t)row * 512 + quad * 8 + s * 32;
    }
    const u16* pb = Wpk + (size_t)ng * 16 * 5120 + lane * 8;

    f32x4 acc[5][8];
    f32x4 zf = {0.f, 0.f, 0.f, 0.f};
#pragma unroll
    for (int g = 0; g < 5; g++)
#pragma unroll
        for (int mf = 0; mf < 8; mf++) acc[g][mf] = zf;

    // prologue: stage chunk 0
#pragma unroll
    for (int i = 0; i < 4; i++)
        gload_lds16(asrc[i], &Abuf[0][(w * 4 + i) * 512]);

#pragma unroll 1
    for (int c = 0; c < 8; c++) {
        __syncthreads();
        if (c < 7) {
#pragma unroll
            for (int i = 0; i < 4; i++)
                gload_lds16(asrc[i] + (c + 1) * 64, &Abuf[(c + 1) & 1][(w * 4 + i) * 512]);
        }
        const u16* ab = &Abuf[c & 1][0];
#pragma unroll
        for (int s = 0; s < 2; s++) {
            int c32 = c * 2 + s;
            short8 bh[5];
#pragma unroll
            for (int g = 0; g < 5; g++)
                bh[g] = *(const short8*)(pb + (size_t)(c32 * 10 + g * 2) * 512);
#pragma unroll
            for (int mf = 0; mf < 8; mf++) {
                short8 ah = *(const short8*)&ab[(s * 8 + mf) * 512 + lane * 8];
#pragma unroll
                for (int g = 0; g < 5; g++)
                    acc[g][mf] = __builtin_amdgcn_mfma_f32_16x16x32_bf16(ah, bh[g], acc[g][mf], 0, 0, 0);
            }
        }
    }

    int n = n0 + w * 16 + l16;
#pragma unroll
    for (int mf = 0; mf < 8; mf++)
#pragma unroll
        for (int r = 0; r < 4; r++) {
            int m = m0 + mf * 16 + quad * 4 + r;
            if (m >= M) continue;
            float fl = fsig(acc[0][mf][r] + bfl[n]);
            float fr = fsig(acc[1][mf][r] + bfr[n]);
            float ig = fsig(acc[2][mf][r] + bi[n]);
            float og = fsig(acc[3][mf][r] + bo[n]);
            float cc = ftanh(acc[4][mf][r] + bc[n]);
            float cl, cr;
            if (LEAF) {
                cl = ftanh(bf2f(Ahi[(size_t)m * 512 + n]));
                cr = ftanh(bf2f(Ahi[(size_t)m * 512 + 256 + n]));
            } else {
                cl = Cin[(size_t)(2 * m) * 256 + n];
                cr = Cin[(size_t)(2 * m + 1) * 256 + n];
            }
            float cn = fl * cl + fr * cr + ig * cc;
            Cout[(size_t)m * 256 + n] = cn;
            float h = og * ftanh(cn);
            u16 hh = f2bf(h);
            u16 hl = f2bf(h - bf2f(hh));
            size_t ai = (size_t)(m >> 1) * 512 + (m & 1) * 256 + n;
            Aohi[ai] = hh;
            Aolo[ai] = hl;
        }
}

// ---------------- small level (M <= 2048): block = 16m x 16n x 5g, waves split K, 3-term -------
__global__ __launch_bounds__(256, 4) void level_small(
    const u16* __restrict__ Ahi, const u16* __restrict__ Alo,
    const float* __restrict__ Cin,
    const u16* __restrict__ Wpk,
    const float* __restrict__ bfl, const float* __restrict__ bfr,
    const float* __restrict__ bi,  const float* __restrict__ bo,
    const float* __restrict__ bc,
    u16* __restrict__ Aohi, u16* __restrict__ Aolo, float* __restrict__ Cout,
    int M)
{
    int tid = threadIdx.x;
    int lane = tid & 63, w = tid >> 6;
    int l16 = lane & 15, quad = lane >> 4;
    int mb = blockIdx.x * 16;
    int ng = blockIdx.y;

    const u16* pah = Ahi + (size_t)(mb + l16) * 512 + quad * 8;
    const u16* pal = Alo + (size_t)(mb + l16) * 512 + quad * 8;
    const u16* pb  = Wpk + (size_t)ng * 16 * 5120 + lane * 8;

    f32x4 acc[5];
    f32x4 zf = {0.f, 0.f, 0.f, 0.f};
#pragma unroll
    for (int g = 0; g < 5; g++) acc[g] = zf;

#pragma unroll
    for (int i = 0; i < 4; i++) {
        int c = w * 4 + i;
        short8 ah = *(const short8*)(pah + c * 32);
        short8 al = *(const short8*)(pal + c * 32);
#pragma unroll
        for (int g = 0; g < 5; g++) {
            short8 bh = *(const short8*)(pb + (size_t)(c * 10 + g * 2) * 512);
            short8 bl = *(const short8*)(pb + (size_t)(c * 10 + g * 2 + 1) * 512);
            acc[g] = __builtin_amdgcn_mfma_f32_16x16x32_bf16(ah, bh, acc[g], 0, 0, 0);
            acc[g] = __builtin_amdgcn_mfma_f32_16x16x32_bf16(al, bh, acc[g], 0, 0, 0);
            acc[g] = __builtin_amdgcn_mfma_f32_16x16x32_bf16(ah, bl, acc[g], 0, 0, 0);
        }
    }

    __shared__ float red[4][5][256];   // 20 KB
#pragma unroll
    for (int g = 0; g < 5; g++)
#pragma unroll
        for (int r = 0; r < 4; r++)
            red[w][g][(quad * 4 + r) * 16 + l16] = acc[g][r];
    __syncthreads();

    int m = mb + (tid >> 4);
    int n = ng * 16 + (tid & 15);
    if (m < M) {
        float z[5];
#pragma unroll
        for (int g = 0; g < 5; g++)
            z[g] = red[0][g][tid] + red[1][g][tid] + red[2][g][tid] + red[3][g][tid];
        float fl = fsig(z[0] + bfl[n]);
        float fr = fsig(z[1] + bfr[n]);
        float ig = fsig(z[2] + bi[n]);
        float og = fsig(z[3] + bo[n]);
        float cc = ftanh(z[4] + bc[n]);
        float cl = Cin[(size_t)(2 * m) * 256 + n];
        float cr = Cin[(size_t)(2 * m + 1) * 256 + n];
        float cn = fl * cl + fr * cr + ig * cc;
        Cout[(size_t)m * 256 + n] = cn;
        float h = og * ftanh(cn);
        u16 hh = f2bf(h);
        u16 hl = f2bf(h - bf2f(hh));
        size_t ai = (size_t)(m >> 1) * 512 + (m & 1) * 256 + n;
        Aohi[ai] = hh;
        Aolo[ai] = hl;
    }
}

// ---------------- classifier ----------------
__global__ void classifier_bf(const u16* __restrict__ Ahi, const u16* __restrict__ Alo,
                              const float* __restrict__ Wcls, const float* __restrict__ bcls,
                              float* __restrict__ out)
{
    int t = threadIdx.x;
    if (t < Bdim * 2) {
        int b = t >> 1, cls = t & 1;
        float s = bcls[cls];
        for (int n = 0; n < Hdim; n++) {
            size_t ai = (size_t)(b >> 1) * 512 + (b & 1) * 256 + n;
            float h = bf2f(Ahi[ai]) + bf2f(Alo[ai]);
            s += h * Wcls[(size_t)n * 2 + cls];
        }
        out[t] = s;
    }
}

extern "C" void kernel_launch(void* const* d_in, const int* in_sizes, int n_in,
                              void* d_out, int out_size, void* d_ws, size_t ws_size,
                              hipStream_t stream) {
    const int*   ids  = (const int*)d_in[0];
    const float* emb  = (const float*)d_in[1];
    const float* Wp   = (const float*)d_in[2];
    const float* bp   = (const float*)d_in[3];
    const float* Wfl  = (const float*)d_in[4];
    const float* bfl  = (const float*)d_in[5];
    const float* Wfr  = (const float*)d_in[6];
    const float* bfr  = (const float*)d_in[7];
    const float* Wi   = (const float*)d_in[8];
    const float* bi   = (const float*)d_in[9];
    const float* Wo   = (const float*)d_in[10];
    const float* bo   = (const float*)d_in[11];
    const float* Wc   = (const float*)d_in[12];
    const float* bc   = (const float*)d_in[13];
    const float* Wcls = (const float*)d_in[14];
    const float* bcls = (const float*)d_in[15];

    u16* Wpk  = (u16*)d_ws;
    u16* Wppk = Wpk + (size_t)256 * 5120;
    unsigned char* base = (unsigned char*)d_ws + (4u << 20);
    unsigned char* R1 = base;
    unsigned char* R2 = base + 33554432;

    pack_weights2<<<256, 256, 0, stream>>>(Wfl, Wfr, Wi, Wo, Wc, Wpk);
    pack_wp2<<<128, 256, 0, stream>>>(Wp, Wppk);

    int M0 = Bdim * Lleaf;
    leaf_mfma2<<<dim3(M0 / 128, 4), 256, 0, stream>>>(ids, emb, Wppk, bp, (u16*)R1);

    const u16* Ain_hi = (const u16*)R1;
    const u16* Ain_lo = nullptr;
    const float* Cin = nullptr;

    int lev = 1;
    for (int M = 32768; M >= 16; M >>= 1, lev++) {
        unsigned char* ob = (lev & 1) ? R2 : R1;
        u16* Aohi = (u16*)ob;
        u16* Aolo = Aohi + (size_t)M * 256;
        float* Cout = (float*)(Aohi + (size_t)M * 512);
        if (lev == 1) {
            level_big<1><<<dim3(M / 128, 4), 256, 0, stream>>>(Ain_hi, nullptr, Wpk,
                                                               bfl, bfr, bi, bo, bc, Aohi, Aolo, Cout, M);
        } else if (M >= 4096) {
            level_big<0><<<dim3(M / 128, 4), 256, 0, stream>>>(Ain_hi, Cin, Wpk,
                                                               bfl, bfr, bi, bo, bc, Aohi, Aolo, Cout, M);
        } else {
            level_small<<<dim3(M / 16, 16), 256, 0, stream>>>(Ain_hi, Ain_lo, Cin, Wpk,
                                                              bfl, bfr, bi, bo, bc, Aohi, Aolo, Cout, M);
        }
        Ain_hi = Aohi; Ain_lo = Aolo; Cin = Cout;
    }

    classifier_bf<<<1, 64, 0, stream>>>(Ain_hi, Ain_lo, Wcls, bcls, (float*)d_out);
}

// Round 11
// 395.113 us; speedup vs baseline: 1.2912x; 1.1128x over previous
//
#include <hip/hip_runtime.h>
#include <hip/hip_bf16.h>

#define Hdim 256
#define Bdim 16
#define Lleaf 4096

typedef unsigned short u16;
typedef __attribute__((ext_vector_type(8))) short short8;
typedef __attribute__((ext_vector_type(4))) float f32x4;

__device__ __forceinline__ u16 f2bf(float x) {
    __hip_bfloat16 b = __float2bfloat16(x);
    return *(u16*)&b;
}
__device__ __forceinline__ float bf2f(u16 u) {
    __hip_bfloat16 b = *(__hip_bfloat16*)&u;
    return __bfloat162float(b);
}
__device__ __forceinline__ float fsig(float x) { return 1.0f / (1.0f + __expf(-x)); }
__device__ __forceinline__ float ftanh(float x) {
    float e = __expf(-2.0f * fabsf(x));
    float t = (1.0f - e) / (1.0f + e);
    return copysignf(t, x);
}

__device__ __forceinline__ void gload_lds16(const u16* gsrc, u16* ldsdst) {
    __builtin_amdgcn_global_load_lds(
        (const __attribute__((address_space(1))) unsigned int*)gsrc,
        (__attribute__((address_space(3))) unsigned int*)ldsdst, 16, 0, 0);
}

// ---------------- weight pack, fragment-major: Wpk[ng][c32][g][t][512] ----------------
__global__ void pack_weights2(const float* __restrict__ Wfl, const float* __restrict__ Wfr,
                              const float* __restrict__ Wi,  const float* __restrict__ Wo,
                              const float* __restrict__ Wc,
                              u16* __restrict__ Wpk)
{
    int blk = blockIdx.x;            // 0..255 = ng*16 + c32
    int ng = blk >> 4, c = blk & 15;
    for (int e = threadIdx.x; e < 5120; e += 256) {
        int g = e >> 10, r = e & 1023;
        int t = r >> 9, s = r & 511;
        int lane = s >> 3, j = s & 7;
        int n = ng * 16 + (lane & 15);
        int k = c * 32 + (lane >> 4) * 8 + j;
        const float* W = (g == 0) ? Wfl : (g == 1) ? Wfr : (g == 2) ? Wi : (g == 3) ? Wo : Wc;
        float x = W[(size_t)k * Hdim + n];
        u16 hi = f2bf(x);
        u16 v = t ? f2bf(x - bf2f(hi)) : hi;
        Wpk[(size_t)blk * 5120 + e] = v;
    }
}

// ---------------- W_proj pack, fragment-major: Wppk[ng][c32][t][512], c32=0..7 ----------------
__global__ void pack_wp2(const float* __restrict__ Wp, u16* __restrict__ Wppk)
{
    int blk = blockIdx.x;            // 0..127 = ng*8 + c32
    int ng = blk >> 3, c = blk & 7;
    for (int e = threadIdx.x; e < 1024; e += 256) {
        int t = e >> 9, s = e & 511;
        int lane = s >> 3, j = s & 7;
        int n = ng * 16 + (lane & 15);
        int k = c * 32 + (lane >> 4) * 8 + j;
        float x = Wp[(size_t)k * Hdim + n];
        u16 hi = f2bf(x);
        u16 v = t ? f2bf(x - bf2f(hi)) : hi;
        Wppk[(size_t)blk * 1024 + e] = v;
    }
}

// ---------------- leaf via MFMA: no LDS, no barriers, B direct from packed Wp (3-term) ---------
__global__ __launch_bounds__(256, 2) void leaf_mfma2(
    const int* __restrict__ ids, const float* __restrict__ emb,
    const u16* __restrict__ Wppk, const float* __restrict__ bp,
    u16* __restrict__ A0hi)
{
    int tid = threadIdx.x;
    int lane = tid & 63, w = tid >> 6;
    int l16 = lane & 15, quad = lane >> 4;
    int m0 = blockIdx.x * 128, ny = blockIdx.y;
    int n0 = ny * 64;

    const float* aptr[2];
#pragma unroll
    for (int mt = 0; mt < 2; mt++) {
        int m = m0 + w * 32 + mt * 16 + l16;
        aptr[mt] = emb + (size_t)ids[m] * 256 + quad * 8;
    }

    f32x4 acc[2][4];
    f32x4 zf = {0.f, 0.f, 0.f, 0.f};
#pragma unroll
    for (int i = 0; i < 2; i++)
#pragma unroll
        for (int j = 0; j < 4; j++) acc[i][j] = zf;

#pragma unroll 1
    for (int c = 0; c < 8; c++) {
        int k0 = c * 32;
        short8 bh[4], bl[4];
#pragma unroll
        for (int nt = 0; nt < 4; nt++) {
            const u16* pb = Wppk + (size_t)(((ny * 4 + nt) * 8 + c) * 2) * 512 + lane * 8;
            bh[nt] = *(const short8*)(pb);
            bl[nt] = *(const short8*)(pb + 512);
        }
        short8 ah[2], al[2];
#pragma unroll
        for (int mt = 0; mt < 2; mt++) {
            float4 a0 = *(const float4*)(aptr[mt] + k0);
            float4 a1 = *(const float4*)(aptr[mt] + k0 + 4);
            float fv[8] = {a0.x, a0.y, a0.z, a0.w, a1.x, a1.y, a1.z, a1.w};
#pragma unroll
            for (int e = 0; e < 8; e++) {
                u16 hv = f2bf(fv[e]);
                u16 lv = f2bf(fv[e] - bf2f(hv));
                ah[mt][e] = (short)hv;
                al[mt][e] = (short)lv;
            }
        }
#pragma unroll
        for (int nt = 0; nt < 4; nt++)
#pragma unroll
            for (int mt = 0; mt < 2; mt++) {
                acc[mt][nt] = __builtin_amdgcn_mfma_f32_16x16x32_bf16(ah[mt], bh[nt], acc[mt][nt], 0, 0, 0);
                acc[mt][nt] = __builtin_amdgcn_mfma_f32_16x16x32_bf16(al[mt], bh[nt], acc[mt][nt], 0, 0, 0);
                acc[mt][nt] = __builtin_amdgcn_mfma_f32_16x16x32_bf16(ah[mt], bl[nt], acc[mt][nt], 0, 0, 0);
            }
    }
#pragma unroll
    for (int mt = 0; mt < 2; mt++)
#pragma unroll
        for (int nt = 0; nt < 4; nt++)
#pragma unroll
            for (int r = 0; r < 4; r++) {
                int m = m0 + w * 32 + mt * 16 + quad * 4 + r;
                int n = n0 + nt * 16 + l16;
                float h = acc[mt][nt][r] + bp[n];
                A0hi[(size_t)(m >> 1) * 512 + (m & 1) * 256 + n] = f2bf(h);
            }
}

// ---------------- big level (M >= 4096): 1-term bf16 GEMM, wave tile 64m x 16n ----------------
// Block 64m x 64n; 4 waves n-split. acc = 5g x 4mf f32x4 = 80 regs (was 160) -> 3 waves/SIMD.
// A dbuf LDS (2 x 8 KB) via global_load_lds; B direct global->VGPR from packed weights.
// WLO: write the Aolo stream (only the level feeding the first small level needs it).
template <int LEAF, int WLO>
__global__ __launch_bounds__(256, 3) void level_big2(
    const u16* __restrict__ Ahi,
    const float* __restrict__ Cin,
    const u16* __restrict__ Wpk,
    const float* __restrict__ bfl, const float* __restrict__ bfr,
    const float* __restrict__ bi,  const float* __restrict__ bo,
    const float* __restrict__ bc,
    u16* __restrict__ Aohi, u16* __restrict__ Aolo, float* __restrict__ Cout,
    int M)
{
    int tid = threadIdx.x;
    int lane = tid & 63, w = tid >> 6;
    int l16 = lane & 15, quad = lane >> 4;
    int m0 = blockIdx.x * 64, n0 = blockIdx.y * 64;
    int ng = blockIdx.y * 4 + w;

    __shared__ u16 Abuf[2][8 * 512];       // 2 x 8 KB (k64 chunk = 8 frags: s*4+mf)

    // per-wave A staging: 2 frags per k64 chunk; fj = w*2+i -> s = fj>>2, mf = fj&3
    const u16* asrc[2];
#pragma unroll
    for (int i = 0; i < 2; i++) {
        int fj = w * 2 + i;
        int s = fj >> 2, mf = fj & 3;
        int row = min(m0 + mf * 16 + l16, M - 1);
        asrc[i] = Ahi + (size_t)row * 512 + quad * 8 + s * 32;
    }
    const u16* pb = Wpk + (size_t)ng * 16 * 5120 + lane * 8;

    f32x4 acc[5][4];
    f32x4 zf = {0.f, 0.f, 0.f, 0.f};
#pragma unroll
    for (int g = 0; g < 5; g++)
#pragma unroll
        for (int mf = 0; mf < 4; mf++) acc[g][mf] = zf;

    // prologue: stage chunk 0
#pragma unroll
    for (int i = 0; i < 2; i++)
        gload_lds16(asrc[i], &Abuf[0][(w * 2 + i) * 512]);

#pragma unroll 1
    for (int c = 0; c < 8; c++) {
        __syncthreads();
        if (c < 7) {
#pragma unroll
            for (int i = 0; i < 2; i++)
                gload_lds16(asrc[i] + (c + 1) * 64, &Abuf[(c + 1) & 1][(w * 2 + i) * 512]);
        }
        const u16* ab = &Abuf[c & 1][0];
#pragma unroll
        for (int s = 0; s < 2; s++) {
            int c32 = c * 2 + s;
            short8 bh[5];
#pragma unroll
            for (int g = 0; g < 5; g++)
                bh[g] = *(const short8*)(pb + (size_t)(c32 * 10 + g * 2) * 512);
#pragma unroll
            for (int mf = 0; mf < 4; mf++) {
                short8 ah = *(const short8*)&ab[(s * 4 + mf) * 512 + lane * 8];
#pragma unroll
                for (int g = 0; g < 5; g++)
                    acc[g][mf] = __builtin_amdgcn_mfma_f32_16x16x32_bf16(ah, bh[g], acc[g][mf], 0, 0, 0);
            }
        }
    }

    int n = n0 + w * 16 + l16;
#pragma unroll
    for (int mf = 0; mf < 4; mf++)
#pragma unroll
        for (int r = 0; r < 4; r++) {
            int m = m0 + mf * 16 + quad * 4 + r;
            if (m >= M) continue;
            float fl = fsig(acc[0][mf][r] + bfl[n]);
            float fr = fsig(acc[1][mf][r] + bfr[n]);
            float ig = fsig(acc[2][mf][r] + bi[n]);
            float og = fsig(acc[3][mf][r] + bo[n]);
            float cc = ftanh(acc[4][mf][r] + bc[n]);
            float cl, cr;
            if (LEAF) {
                cl = ftanh(bf2f(Ahi[(size_t)m * 512 + n]));
                cr = ftanh(bf2f(Ahi[(size_t)m * 512 + 256 + n]));
            } else {
                cl = Cin[(size_t)(2 * m) * 256 + n];
                cr = Cin[(size_t)(2 * m + 1) * 256 + n];
            }
            float cn = fl * cl + fr * cr + ig * cc;
            Cout[(size_t)m * 256 + n] = cn;
            float h = og * ftanh(cn);
            u16 hh = f2bf(h);
            size_t ai = (size_t)(m >> 1) * 512 + (m & 1) * 256 + n;
            Aohi[ai] = hh;
            if (WLO) Aolo[ai] = f2bf(h - bf2f(hh));
        }
}

// ---------------- small level (M <= 2048): block = 16m x 16n x 5g, waves split K, 3-term -------
__global__ __launch_bounds__(256, 4) void level_small(
    const u16* __restrict__ Ahi, const u16* __restrict__ Alo,
    const float* __restrict__ Cin,
    const u16* __restrict__ Wpk,
    const float* __restrict__ bfl, const float* __restrict__ bfr,
    const float* __restrict__ bi,  const float* __restrict__ bo,
    const float* __restrict__ bc,
    u16* __restrict__ Aohi, u16* __restrict__ Aolo, float* __restrict__ Cout,
    int M)
{
    int tid = threadIdx.x;
    int lane = tid & 63, w = tid >> 6;
    int l16 = lane & 15, quad = lane >> 4;
    int mb = blockIdx.x * 16;
    int ng = blockIdx.y;

    const u16* pah = Ahi + (size_t)(mb + l16) * 512 + quad * 8;
    const u16* pal = Alo + (size_t)(mb + l16) * 512 + quad * 8;
    const u16* pb  = Wpk + (size_t)ng * 16 * 5120 + lane * 8;

    f32x4 acc[5];
    f32x4 zf = {0.f, 0.f, 0.f, 0.f};
#pragma unroll
    for (int g = 0; g < 5; g++) acc[g] = zf;

#pragma unroll
    for (int i = 0; i < 4; i++) {
        int c = w * 4 + i;
        short8 ah = *(const short8*)(pah + c * 32);
        short8 al = *(const short8*)(pal + c * 32);
#pragma unroll
        for (int g = 0; g < 5; g++) {
            short8 bh = *(const short8*)(pb + (size_t)(c * 10 + g * 2) * 512);
            short8 bl = *(const short8*)(pb + (size_t)(c * 10 + g * 2 + 1) * 512);
            acc[g] = __builtin_amdgcn_mfma_f32_16x16x32_bf16(ah, bh, acc[g], 0, 0, 0);
            acc[g] = __builtin_amdgcn_mfma_f32_16x16x32_bf16(al, bh, acc[g], 0, 0, 0);
            acc[g] = __builtin_amdgcn_mfma_f32_16x16x32_bf16(ah, bl, acc[g], 0, 0, 0);
        }
    }

    __shared__ float red[4][5][256];   // 20 KB
#pragma unroll
    for (int g = 0; g < 5; g++)
#pragma unroll
        for (int r = 0; r < 4; r++)
            red[w][g][(quad * 4 + r) * 16 + l16] = acc[g][r];
    __syncthreads();

    int m = mb + (tid >> 4);
    int n = ng * 16 + (tid & 15);
    if (m < M) {
        float z[5];
#pragma unroll
        for (int g = 0; g < 5; g++)
            z[g] = red[0][g][tid] + red[1][g][tid] + red[2][g][tid] + red[3][g][tid];
        float fl = fsig(z[0] + bfl[n]);
        float fr = fsig(z[1] + bfr[n]);
        float ig = fsig(z[2] + bi[n]);
        float og = fsig(z[3] + bo[n]);
        float cc = ftanh(z[4] + bc[n]);
        float cl = Cin[(size_t)(2 * m) * 256 + n];
        float cr = Cin[(size_t)(2 * m + 1) * 256 + n];
        float cn = fl * cl + fr * cr + ig * cc;
        Cout[(size_t)m * 256 + n] = cn;
        float h = og * ftanh(cn);
        u16 hh = f2bf(h);
        u16 hl = f2bf(h - bf2f(hh));
        size_t ai = (size_t)(m >> 1) * 512 + (m & 1) * 256 + n;
        Aohi[ai] = hh;
        Aolo[ai] = hl;
    }
}

// ---------------- classifier ----------------
__global__ void classifier_bf(const u16* __restrict__ Ahi, const u16* __restrict__ Alo,
                              const float* __restrict__ Wcls, const float* __restrict__ bcls,
                              float* __restrict__ out)
{
    int t = threadIdx.x;
    if (t < Bdim * 2) {
        int b = t >> 1, cls = t & 1;
        float s = bcls[cls];
        for (int n = 0; n < Hdim; n++) {
            size_t ai = (size_t)(b >> 1) * 512 + (b & 1) * 256 + n;
            float h = bf2f(Ahi[ai]) + bf2f(Alo[ai]);
            s += h * Wcls[(size_t)n * 2 + cls];
        }
        out[t] = s;
    }
}

extern "C" void kernel_launch(void* const* d_in, const int* in_sizes, int n_in,
                              void* d_out, int out_size, void* d_ws, size_t ws_size,
                              hipStream_t stream) {
    const int*   ids  = (const int*)d_in[0];
    const float* emb  = (const float*)d_in[1];
    const float* Wp   = (const float*)d_in[2];
    const float* bp   = (const float*)d_in[3];
    const float* Wfl  = (const float*)d_in[4];
    const float* bfl  = (const float*)d_in[5];
    const float* Wfr  = (const float*)d_in[6];
    const float* bfr  = (const float*)d_in[7];
    const float* Wi   = (const float*)d_in[8];
    const float* bi   = (const float*)d_in[9];
    const float* Wo   = (const float*)d_in[10];
    const float* bo   = (const float*)d_in[11];
    const float* Wc   = (const float*)d_in[12];
    const float* bc   = (const float*)d_in[13];
    const float* Wcls = (const float*)d_in[14];
    const float* bcls = (const float*)d_in[15];

    u16* Wpk  = (u16*)d_ws;
    u16* Wppk = Wpk + (size_t)256 * 5120;
    unsigned char* base = (unsigned char*)d_ws + (4u << 20);
    unsigned char* R1 = base;
    unsigned char* R2 = base + 33554432;

    pack_weights2<<<256, 256, 0, stream>>>(Wfl, Wfr, Wi, Wo, Wc, Wpk);
    pack_wp2<<<128, 256, 0, stream>>>(Wp, Wppk);

    int M0 = Bdim * Lleaf;
    leaf_mfma2<<<dim3(M0 / 128, 4), 256, 0, stream>>>(ids, emb, Wppk, bp, (u16*)R1);

    const u16* Ain_hi = (const u16*)R1;
    const u16* Ain_lo = nullptr;
    const float* Cin = nullptr;

    int lev = 1;
    for (int M = 32768; M >= 16; M >>= 1, lev++) {
        unsigned char* ob = (lev & 1) ? R2 : R1;
        u16* Aohi = (u16*)ob;
        u16* Aolo = Aohi + (size_t)M * 256;
        float* Cout = (float*)(Aohi + (size_t)M * 512);
        if (lev == 1) {
            level_big2<1, 0><<<dim3(M / 64, 4), 256, 0, stream>>>(Ain_hi, nullptr, Wpk,
                                                                  bfl, bfr, bi, bo, bc, Aohi, Aolo, Cout, M);
        } else if (M > 4096) {
            level_big2<0, 0><<<dim3(M / 64, 4), 256, 0, stream>>>(Ain_hi, Cin, Wpk,
                                                                  bfl, bfr, bi, bo, bc, Aohi, Aolo, Cout, M);
        } else if (M == 4096) {
            level_big2<0, 1><<<dim3(M / 64, 4), 256, 0, stream>>>(Ain_hi, Cin, Wpk,
                                                                  bfl, bfr, bi, bo, bc, Aohi, Aolo, Cout, M);
        } else {
            level_small<<<dim3(M / 16, 16), 256, 0, stream>>>(Ain_hi, Ain_lo, Cin, Wpk,
                                                              bfl, bfr, bi, bo, bc, Aohi, Aolo, Cout, M);
        }
        Ain_hi = Aohi; Ain_lo = Aolo; Cin = Cout;
    }

    classifier_bf<<<1, 64, 0, stream>>>(Ain_hi, Ain_lo, Wcls, bcls, (float*)d_out);
}